// Round 1
// baseline (332.657 us; speedup 1.0000x reference)
//
#include <hip/hip_runtime.h>

// SpectralPooling: x (4,32,64,64,64) f32 -> out (4,32,48,48,48) f32
// Composed per-axis matrix: A[a,n] = sum_{k<32} M48[k,a] * M64[k,n]  (48x64)
// y = A x_D A x_H A x_W x  (separable, 128 volumes)

// ---------------- matrix generation (once per launch, tiny) ----------------
__global__ __launch_bounds__(256) void gen_A_kernel(float* __restrict__ At) {
    int tid = threadIdx.x;
    const double PI = 3.14159265358979323846;
    const double INV_SQRT2 = 0.70710678118654752440;
    for (int idx = tid; idx < 64 * 48; idx += 256) {
        int n = idx / 48;   // input index 0..63
        int a = idx % 48;   // output index 0..47
        double s = 0.0;
        for (int k = 0; k < 32; ++k) {
            double c48 = cos(PI * (a + 0.5) * k / 48.0) * sqrt(2.0 / 48.0);
            double c64 = cos(PI * (n + 0.5) * k / 64.0) * sqrt(2.0 / 64.0);
            if (k == 0) { c48 *= INV_SQRT2; c64 *= INV_SQRT2; }
            s += c48 * c64;
        }
        // At[n][a] = A[a][n]
        At[idx] = (float)s;
    }
}

// ---------------- K1: per (b,c,d) slice, transform W then H ----------------
// x slice 64x64 -> t1 64x48 (W) -> t2 48x48 (H), write to ws y2[bc][d][a1][a2]
__global__ __launch_bounds__(256) void k1_hw(const float* __restrict__ x,
                                            const float* __restrict__ At,
                                            float* __restrict__ y2) {
    __shared__ float sA[64 * 48];      // At[n][a], uniform b128 reads
    __shared__ float sX[64 * 65];      // x[h][w], stride 65 (bank-spread)
    __shared__ float sT[64 * 49 + 16]; // t1[h][a2], stride 49 (+slack for clamped lanes)

    const int tid = threadIdx.x;
    const int blk = blockIdx.x;          // bc*64 + d

    // load A (3072 floats, coalesced; L2-hot after first blocks)
    for (int i = tid; i < 64 * 48; i += 256) sA[i] = At[i];

    // load x slice: 4096 floats as float4
    const float4* xg = (const float4*)(x + (size_t)blk * 4096);
    #pragma unroll
    for (int j = 0; j < 4; ++j) {
        int v = tid + 256 * j;           // 0..1023
        float4 t = xg[v];
        int h = v >> 4;
        int w4 = (v & 15) << 2;
        float* p = &sX[h * 65 + w4];
        p[0] = t.x; p[1] = t.y; p[2] = t.z; p[3] = t.w;
    }
    __syncthreads();

    const int g = tid >> 6;      // wave id: owns output group a in [g*12, g*12+12)
    const int lane = tid & 63;

    // ---- stage 1 (W): t1[h=lane][a2=g*12+j] = sum_w A[a2,w] * x[h,w]
    float acc[12];
    #pragma unroll
    for (int j = 0; j < 12; ++j) acc[j] = 0.f;

    #pragma unroll 8
    for (int w = 0; w < 64; ++w) {
        float xv = sX[lane * 65 + w];
        const float4* a4 = (const float4*)&sA[w * 48 + g * 12]; // 16B aligned
        float4 A0 = a4[0], A1 = a4[1], A2 = a4[2];
        acc[0]  += A0.x * xv; acc[1]  += A0.y * xv; acc[2]  += A0.z * xv; acc[3]  += A0.w * xv;
        acc[4]  += A1.x * xv; acc[5]  += A1.y * xv; acc[6]  += A1.z * xv; acc[7]  += A1.w * xv;
        acc[8]  += A2.x * xv; acc[9]  += A2.y * xv; acc[10] += A2.z * xv; acc[11] += A2.w * xv;
    }
    #pragma unroll
    for (int j = 0; j < 12; ++j) sT[lane * 49 + g * 12 + j] = acc[j];
    __syncthreads();

    // ---- stage 2 (H): t2[a1=g*12+j][a2=lane] = sum_h A[a1,h] * t1[h,a2]
    const int l2 = (lane < 48) ? lane : 47;   // clamp idle lanes (no OOB)
    float acc2[12];
    #pragma unroll
    for (int j = 0; j < 12; ++j) acc2[j] = 0.f;

    #pragma unroll 8
    for (int h = 0; h < 64; ++h) {
        float tv = sT[h * 49 + l2];
        const float4* a4 = (const float4*)&sA[h * 48 + g * 12];
        float4 A0 = a4[0], A1 = a4[1], A2 = a4[2];
        acc2[0]  += A0.x * tv; acc2[1]  += A0.y * tv; acc2[2]  += A0.z * tv; acc2[3]  += A0.w * tv;
        acc2[4]  += A1.x * tv; acc2[5]  += A1.y * tv; acc2[6]  += A1.z * tv; acc2[7]  += A1.w * tv;
        acc2[8]  += A2.x * tv; acc2[9]  += A2.y * tv; acc2[10] += A2.z * tv; acc2[11] += A2.w * tv;
    }

    if (lane < 48) {
        float* dst = y2 + (size_t)blk * 2304 + lane;   // y2[bc][d][a1][a2]
        #pragma unroll
        for (int j = 0; j < 12; ++j) dst[(g * 12 + j) * 48] = acc2[j];
    }
}

// ---------------- K2: per (bc, a1), transform D ----------------
// out[bc][a0][a1][a2] = sum_d A[a0,d] * y2[bc][d][a1][a2]
__global__ __launch_bounds__(256) void k2_d(const float* __restrict__ y2,
                                           const float* __restrict__ At,
                                           float* __restrict__ out) {
    __shared__ float sA[64 * 48];
    __shared__ float sT[64 * 48];   // t[d][a2]

    const int tid = threadIdx.x;
    const int blk = blockIdx.x;
    const int bc = blk / 48;
    const int a1 = blk % 48;

    for (int i = tid; i < 64 * 48; i += 256) sA[i] = At[i];

    #pragma unroll
    for (int j = 0; j < 12; ++j) {
        int idx = tid + 256 * j;        // 0..3071
        int d  = idx / 48;
        int a2 = idx % 48;
        sT[idx] = y2[((size_t)(bc * 64 + d) * 48 + a1) * 48 + a2];
    }
    __syncthreads();

    const int g = tid >> 6;
    const int lane = tid & 63;
    const int l2 = (lane < 48) ? lane : 47;

    float acc[12];
    #pragma unroll
    for (int j = 0; j < 12; ++j) acc[j] = 0.f;

    #pragma unroll 8
    for (int d = 0; d < 64; ++d) {
        float tv = sT[d * 48 + l2];
        const float4* a4 = (const float4*)&sA[d * 48 + g * 12];
        float4 A0 = a4[0], A1 = a4[1], A2 = a4[2];
        acc[0]  += A0.x * tv; acc[1]  += A0.y * tv; acc[2]  += A0.z * tv; acc[3]  += A0.w * tv;
        acc[4]  += A1.x * tv; acc[5]  += A1.y * tv; acc[6]  += A1.z * tv; acc[7]  += A1.w * tv;
        acc[8]  += A2.x * tv; acc[9]  += A2.y * tv; acc[10] += A2.z * tv; acc[11] += A2.w * tv;
    }

    if (lane < 48) {
        #pragma unroll
        for (int j = 0; j < 12; ++j) {
            int a0 = g * 12 + j;
            out[((size_t)(bc * 48 + a0) * 48 + a1) * 48 + lane] = acc[j];
        }
    }
}

extern "C" void kernel_launch(void* const* d_in, const int* in_sizes, int n_in,
                              void* d_out, int out_size, void* d_ws, size_t ws_size,
                              hipStream_t stream) {
    const float* x = (const float*)d_in[0];
    float* out = (float*)d_out;

    float* At = (float*)d_ws;                               // 12 KiB
    float* y2 = (float*)((char*)d_ws + 65536);              // 128*64*48*48*4 = 72 MiB

    gen_A_kernel<<<1, 256, 0, stream>>>(At);
    k1_hw<<<128 * 64, 256, 0, stream>>>(x, At, y2);
    k2_d<<<128 * 48, 256, 0, stream>>>(y2, At, out);
}

// Round 2
// 125.897 us; speedup vs baseline: 2.6423x; 2.6423x over previous
//
#include <hip/hip_runtime.h>

// SpectralPooling: x (4,32,64,64,64) f32 -> out (4,32,48,48,48) f32
// Composed matrix A[a,n] = sum_{k<32} M48[k,a]*M64[k,n]  (48x64), applied per axis.
// Layout in ws: At[n][a] (row n in [0,64), col a in [0,48)) -- but kernels read
// A by rows of n with a-groups, i.e. At[n*48 + a].

// ---------------- matrix generation ----------------
// Exact integer angle reduction: cos(pi*(n+0.5)*k/N) = cos(pi*m/(2N)), m=(2n+1)k mod 4N.
__global__ __launch_bounds__(256) void gen_A_kernel(float* __restrict__ At) {
    int idx = blockIdx.x * 256 + threadIdx.x;   // 0..3071
    if (idx >= 64 * 48) return;
    int n = idx / 48;   // input index 0..63
    int a = idx % 48;   // output index 0..47
    const float PI = 3.14159265358979323846f;
    const float s48 = 0.20412414523193150818f;  // sqrt(2/48)
    const float s64 = 0.17677669529663688110f;  // sqrt(2/64)
    const float INV_SQRT2 = 0.70710678118654752440f;
    float s = 0.f;
    for (int k = 0; k < 32; ++k) {
        int m48 = ((2 * a + 1) * k) % 192;      // 4*48
        int m64 = ((2 * n + 1) * k) % 256;      // 4*64
        float c48 = __cosf(PI * (float)m48 / 96.0f) * s48;
        float c64 = __cosf(PI * (float)m64 / 128.0f) * s64;
        if (k == 0) { c48 *= INV_SQRT2; c64 *= INV_SQRT2; }
        s += c48 * c64;
    }
    At[idx] = s;
}

// ---------------- K1: per (b,c,d) slice: W-transform then H-transform --------
// x slice 64x64 -> t1[a2][h] (W) -> t2[a1][a2] (H) -> y2[bc][d][a1][a2]
__global__ __launch_bounds__(256) void k1_hw(const float* __restrict__ x,
                                             const float* __restrict__ At,
                                             float* __restrict__ y2) {
    __shared__ __align__(16) float sX[64 * 68];   // x[h][w], stride 68 (16B-aligned rows, uniform banks)
    __shared__ __align__(16) float sT[48 * 68];   // t1[a2][h]

    const int tid = threadIdx.x;
    const int blk = blockIdx.x;          // bc*64 + d

    // load x slice: 4096 floats as float4 -> sX rows stride 68
    const float4* xg = (const float4*)(x + (size_t)blk * 4096);
    #pragma unroll
    for (int j = 0; j < 4; ++j) {
        int v = tid + 256 * j;           // 0..1023
        float4 t = xg[v];
        int h = v >> 4;
        int w4 = v & 15;
        *(float4*)&sX[h * 68 + w4 * 4] = t;
    }
    __syncthreads();

    const int g = __builtin_amdgcn_readfirstlane(tid >> 6);  // wave id (uniform -> SGPR)
    const int lane = tid & 63;
    const float* __restrict__ Ag = At + g * 12;  // this wave's 12 output columns

    // ---- stage 1 (W): t1[a2=g*12+j][h=lane] = sum_w A[a2,w] * x[h,w]
    float acc[12];
    #pragma unroll
    for (int j = 0; j < 12; ++j) acc[j] = 0.f;

    #pragma unroll 2
    for (int w4 = 0; w4 < 16; ++w4) {
        float4 xv = *(const float4*)&sX[lane * 68 + w4 * 4];
        #pragma unroll
        for (int r = 0; r < 4; ++r) {
            int w = w4 * 4 + r;
            float xs = (r == 0) ? xv.x : (r == 1) ? xv.y : (r == 2) ? xv.z : xv.w;
            const float4* a4 = (const float4*)(Ag + w * 48);   // uniform -> s_load
            float4 A0 = a4[0], A1 = a4[1], A2 = a4[2];
            acc[0]  += A0.x * xs; acc[1]  += A0.y * xs; acc[2]  += A0.z * xs; acc[3]  += A0.w * xs;
            acc[4]  += A1.x * xs; acc[5]  += A1.y * xs; acc[6]  += A1.z * xs; acc[7]  += A1.w * xs;
            acc[8]  += A2.x * xs; acc[9]  += A2.y * xs; acc[10] += A2.z * xs; acc[11] += A2.w * xs;
        }
    }
    #pragma unroll
    for (int j = 0; j < 12; ++j) sT[(g * 12 + j) * 68 + lane] = acc[j];
    __syncthreads();

    // ---- stage 2 (H): t2[a1=g*12+j][a2=lane] = sum_h A[a1,h] * t1[a2][h]
    const int l2 = (lane < 48) ? lane : 47;   // clamp idle lanes (no OOB)
    float acc2[12];
    #pragma unroll
    for (int j = 0; j < 12; ++j) acc2[j] = 0.f;

    #pragma unroll 2
    for (int h4 = 0; h4 < 16; ++h4) {
        float4 tv = *(const float4*)&sT[l2 * 68 + h4 * 4];
        #pragma unroll
        for (int r = 0; r < 4; ++r) {
            int h = h4 * 4 + r;
            float ts = (r == 0) ? tv.x : (r == 1) ? tv.y : (r == 2) ? tv.z : tv.w;
            const float4* a4 = (const float4*)(Ag + h * 48);
            float4 A0 = a4[0], A1 = a4[1], A2 = a4[2];
            acc2[0]  += A0.x * ts; acc2[1]  += A0.y * ts; acc2[2]  += A0.z * ts; acc2[3]  += A0.w * ts;
            acc2[4]  += A1.x * ts; acc2[5]  += A1.y * ts; acc2[6]  += A1.z * ts; acc2[7]  += A1.w * ts;
            acc2[8]  += A2.x * ts; acc2[9]  += A2.y * ts; acc2[10] += A2.z * ts; acc2[11] += A2.w * ts;
        }
    }

    if (lane < 48) {
        float* dst = y2 + (size_t)blk * 2304 + lane;   // y2[bc][d][a1][a2]
        #pragma unroll
        for (int j = 0; j < 12; ++j) dst[(g * 12 + j) * 48] = acc2[j];
    }
}

// ---------------- K2: per (bc, a1): D-transform ----------------
// out[bc][a0][a1][a2] = sum_d A[a0,d] * y2[bc][d][a1][a2]
__global__ __launch_bounds__(256) void k2_d(const float* __restrict__ y2,
                                            const float* __restrict__ At,
                                            float* __restrict__ out) {
    __shared__ __align__(16) float sT[64 * 48];   // t[d][a2]

    const int tid = threadIdx.x;
    const int blk = blockIdx.x;
    const int bc = blk / 48;
    const int a1 = blk % 48;

    // load 64x48 slice as float4 (each row of 48 floats = 12 float4, 16B-aligned)
    const float4* yg = (const float4*)(y2 + ((size_t)bc * 64 * 48 + a1) * 48);
    float4* sT4 = (float4*)sT;
    #pragma unroll
    for (int jj = 0; jj < 3; ++jj) {
        int idx4 = tid + 256 * jj;       // 0..767
        int d = idx4 / 12;
        int c4 = idx4 % 12;
        sT4[idx4] = yg[(size_t)d * (48 * 48 / 4) + c4];
    }
    __syncthreads();

    const int g = __builtin_amdgcn_readfirstlane(tid >> 6);
    const int lane = tid & 63;
    const int l2 = (lane < 48) ? lane : 47;
    const float* __restrict__ Ag = At + g * 12;

    float acc[12];
    #pragma unroll
    for (int j = 0; j < 12; ++j) acc[j] = 0.f;

    #pragma unroll 4
    for (int d = 0; d < 64; ++d) {
        float tv = sT[d * 48 + l2];                  // contiguous across lanes
        const float4* a4 = (const float4*)(Ag + d * 48);
        float4 A0 = a4[0], A1 = a4[1], A2 = a4[2];
        acc[0]  += A0.x * tv; acc[1]  += A0.y * tv; acc[2]  += A0.z * tv; acc[3]  += A0.w * tv;
        acc[4]  += A1.x * tv; acc[5]  += A1.y * tv; acc[6]  += A1.z * tv; acc[7]  += A1.w * tv;
        acc[8]  += A2.x * tv; acc[9]  += A2.y * tv; acc[10] += A2.z * tv; acc[11] += A2.w * tv;
    }

    if (lane < 48) {
        #pragma unroll
        for (int j = 0; j < 12; ++j) {
            int a0 = g * 12 + j;
            out[((size_t)(bc * 48 + a0) * 48 + a1) * 48 + lane] = acc[j];
        }
    }
}

extern "C" void kernel_launch(void* const* d_in, const int* in_sizes, int n_in,
                              void* d_out, int out_size, void* d_ws, size_t ws_size,
                              hipStream_t stream) {
    const float* x = (const float*)d_in[0];
    float* out = (float*)d_out;

    float* At = (float*)d_ws;                               // 12 KiB
    float* y2 = (float*)((char*)d_ws + 65536);              // 128*64*48*48*4 = 72 MiB

    gen_A_kernel<<<12, 256, 0, stream>>>(At);
    k1_hw<<<128 * 64, 256, 0, stream>>>(x, At, y2);
    k2_d<<<128 * 48, 256, 0, stream>>>(y2, At, out);
}

// Round 3
// 70.817 us; speedup vs baseline: 4.6974x; 1.7778x over previous
//
#include <hip/hip_runtime.h>

// SpectralPooling via split-bf16 MFMA.
// y = A x_D A x_H A x_W x, A = 48x64 composed (truncate32 + iDCT48) matrix.
// All stages use v_mfma_f32_16x16x32_bf16 tiles (M,N=16, K=32).
// Fragment layouts (m89-verified): A-op: row=lane&15, k=8*(lane>>4)+j.
// B-op: col=lane&15, k=8*(lane>>4)+j. D: col=lane&15, row=4*(lane>>4)+reg.

typedef __attribute__((ext_vector_type(8))) short short8;
typedef __attribute__((ext_vector_type(4))) float f32x4;
typedef __attribute__((ext_vector_type(4))) unsigned int u32x4;

static __device__ __forceinline__ unsigned short f2bf(float f) {
    unsigned int u = __float_as_uint(f);
    u += 0x7fffu + ((u >> 16) & 1u);          // RNE
    return (unsigned short)(u >> 16);
}
static __device__ __forceinline__ float bf2f(unsigned short h) {
    return __uint_as_float(((unsigned int)h) << 16);
}

// Table: tbl[s][ks][t][lane][j], s=hi/lo split, ks=k-step(32), t=16-col tile.
// Element = split_s( At[k][a] ), k = 8*(lane>>4)+j+32*ks, a = 16*t+(lane&15).
// Serves as: stage-W B-frag (k=w, a=a2), stage-H A-frag (k=h, a=a1),
// stage-D A-frag (k=d, a=a0).  One 12 KB table for everything.
static __device__ __forceinline__ short8 ldtbl(const unsigned short* __restrict__ tbl,
                                               int s, int ks, int t, int l) {
    return *(const short8*)(tbl + (((s * 2 + ks) * 3 + t) * 64 + l) * 8);
}

__global__ __launch_bounds__(256) void gen_tbl(unsigned short* __restrict__ tbl) {
    int i = blockIdx.x * 256 + threadIdx.x;     // 0..3071, bijective with (ks,t,lane,j)
    int j = i & 7;
    int lane = (i >> 3) & 63;
    int tks = i >> 9;                           // ks*3 + t
    int t = tks % 3, ks = tks / 3;
    int k = 8 * (lane >> 4) + j + 32 * ks;      // 0..63
    int a = 16 * t + (lane & 15);               // 0..47
    const float PI = 3.14159265358979323846f;
    const float s48 = 0.20412414523193150818f;  // sqrt(2/48)
    const float s64 = 0.17677669529663688110f;  // sqrt(2/64)
    float s = 0.f;
    for (int kk = 0; kk < 32; ++kk) {
        int m48 = ((2 * a + 1) * kk) % 192;     // exact angle reduction mod 4N
        int m64 = ((2 * k + 1) * kk) % 256;
        float c48 = cosf(PI * (float)m48 / 96.0f) * s48;
        float c64 = cosf(PI * (float)m64 / 128.0f) * s64;
        if (kk == 0) { c48 *= 0.70710678118654752440f; c64 *= 0.70710678118654752440f; }
        s += c48 * c64;
    }
    unsigned short hi = f2bf(s);
    unsigned short lo = f2bf(s - bf2f(hi));
    tbl[i] = hi;            // s=0 slab
    tbl[i + 3072] = lo;     // s=1 slab
}

// ---------------- K1: per (bc,d) slice: W then H, both on MFMA ----------------
__global__ __launch_bounds__(256) void k1_wh(const float* __restrict__ x,
                                             const unsigned short* __restrict__ tbl,
                                             unsigned short* __restrict__ y2) {
    __shared__ unsigned int sC[48 * 68];   // C1^T [a2][h], packed hi|lo<<16, stride 68 u32

    const int tid = threadIdx.x;
    const int blk = blockIdx.x;                         // bc*64 + d
    const int g = __builtin_amdgcn_readfirstlane(tid >> 6);
    const int l = tid & 63;
    const int r = l & 15;
    const int kq = l >> 4;

    // ---- stage W: C1[h][a2] = sum_w x[h][w] * At[w][a2]; wave g owns h rows [16g,16g+16)
    f32x4 z = {0.f, 0.f, 0.f, 0.f};
    f32x4 acc0 = z, acc1 = z, acc2 = z;
    const float* xb = x + (size_t)blk * 4096 + (size_t)(16 * g + r) * 64 + kq * 8;
    #pragma unroll
    for (int ks = 0; ks < 2; ++ks) {
        float4 xa = *(const float4*)(xb + 32 * ks);
        float4 xc = *(const float4*)(xb + 32 * ks + 4);
        float v[8] = {xa.x, xa.y, xa.z, xa.w, xc.x, xc.y, xc.z, xc.w};
        short8 xh, xl;
        #pragma unroll
        for (int j = 0; j < 8; ++j) {
            unsigned short h = f2bf(v[j]);
            xh[j] = (short)h;
            xl[j] = (short)f2bf(v[j] - bf2f(h));
        }
        #pragma unroll
        for (int t = 0; t < 3; ++t) {
            short8 wh = ldtbl(tbl, 0, ks, t, l);
            short8 wl = ldtbl(tbl, 1, ks, t, l);
            f32x4 a = (t == 0) ? acc0 : (t == 1) ? acc1 : acc2;
            a = __builtin_amdgcn_mfma_f32_16x16x32_bf16(xh, wh, a, 0, 0, 0);
            a = __builtin_amdgcn_mfma_f32_16x16x32_bf16(xl, wh, a, 0, 0, 0);
            a = __builtin_amdgcn_mfma_f32_16x16x32_bf16(xh, wl, a, 0, 0, 0);
            if (t == 0) acc0 = a; else if (t == 1) acc1 = a; else acc2 = a;
        }
    }
    // store C1^T packed (hi,lo) to LDS: lane holds C1[h=16g+4kq+rr][a2=16t+r]
    #pragma unroll
    for (int t = 0; t < 3; ++t) {
        f32x4 a = (t == 0) ? acc0 : (t == 1) ? acc1 : acc2;
        u32x4 pk;
        #pragma unroll
        for (int rr = 0; rr < 4; ++rr) {
            float vv = a[rr];
            unsigned short h = f2bf(vv);
            unsigned short lo = f2bf(vv - bf2f(h));
            pk[rr] = (unsigned int)h | ((unsigned int)lo << 16);
        }
        *(u32x4*)&sC[(16 * t + r) * 68 + 16 * g + 4 * kq] = pk;   // 4 consecutive h
    }
    __syncthreads();

    // ---- stage H: C2[a1][a2] = sum_h At[h][a1] * C1[h][a2]
    // B-frag (n,ks): 8 consecutive u32 at sC[(16n+r)*68 + 8kq + 32ks]
    auto loadB = [&](int n, int ks, short8& ch, short8& cl) {
        const unsigned int* bp = &sC[(16 * n + r) * 68 + 8 * kq + 32 * ks];
        u32x4 u0 = *(const u32x4*)bp;
        u32x4 u1 = *(const u32x4*)(bp + 4);
        #pragma unroll
        for (int e = 0; e < 4; ++e) {
            ch[e]     = (short)(u0[e] & 0xffffu);
            cl[e]     = (short)(u0[e] >> 16);
            ch[4 + e] = (short)(u1[e] & 0xffffu);
            cl[4 + e] = (short)(u1[e] >> 16);
        }
    };
    auto storeY = [&](int m, int n, f32x4 c) {
        unsigned short* dst = y2 + (size_t)blk * 2304 + (size_t)(16 * m + 4 * kq) * 48 + 16 * n + r;
        #pragma unroll
        for (int rr = 0; rr < 4; ++rr) dst[(size_t)rr * 48] = f2bf(c[rr]);
    };

    if (g < 3) {
        // wave g: tiles (m=g, n=0) and (m=g, n=1)
        f32x4 c0 = z, c1 = z;
        #pragma unroll
        for (int ks = 0; ks < 2; ++ks) {
            short8 ah = ldtbl(tbl, 0, ks, g, l);
            short8 al = ldtbl(tbl, 1, ks, g, l);
            short8 ch, cl;
            loadB(0, ks, ch, cl);
            c0 = __builtin_amdgcn_mfma_f32_16x16x32_bf16(ah, ch, c0, 0, 0, 0);
            c0 = __builtin_amdgcn_mfma_f32_16x16x32_bf16(al, ch, c0, 0, 0, 0);
            c0 = __builtin_amdgcn_mfma_f32_16x16x32_bf16(ah, cl, c0, 0, 0, 0);
            loadB(1, ks, ch, cl);
            c1 = __builtin_amdgcn_mfma_f32_16x16x32_bf16(ah, ch, c1, 0, 0, 0);
            c1 = __builtin_amdgcn_mfma_f32_16x16x32_bf16(al, ch, c1, 0, 0, 0);
            c1 = __builtin_amdgcn_mfma_f32_16x16x32_bf16(ah, cl, c1, 0, 0, 0);
        }
        storeY(g, 0, c0);
        storeY(g, 1, c1);
    } else {
        // wave 3: column n=2, tiles m=0,1,2 (B-frag shared across m)
        f32x4 t0 = z, t1 = z, t2 = z;
        #pragma unroll
        for (int ks = 0; ks < 2; ++ks) {
            short8 ch, cl;
            loadB(2, ks, ch, cl);
            #pragma unroll
            for (int m = 0; m < 3; ++m) {
                short8 ah = ldtbl(tbl, 0, ks, m, l);
                short8 al = ldtbl(tbl, 1, ks, m, l);
                f32x4 a = (m == 0) ? t0 : (m == 1) ? t1 : t2;
                a = __builtin_amdgcn_mfma_f32_16x16x32_bf16(ah, ch, a, 0, 0, 0);
                a = __builtin_amdgcn_mfma_f32_16x16x32_bf16(al, ch, a, 0, 0, 0);
                a = __builtin_amdgcn_mfma_f32_16x16x32_bf16(ah, cl, a, 0, 0, 0);
                if (m == 0) t0 = a; else if (m == 1) t1 = a; else t2 = a;
            }
        }
        storeY(0, 2, t0);
        storeY(1, 2, t1);
        storeY(2, 2, t2);
    }
}

// ---------------- K2: D-transform. block=(bc,quad), wave g -> a1=quad*4+g ------
// out[a0][a1][a2] = sum_d At[d][a0] * y2[d][a1][a2]
__global__ __launch_bounds__(256) void k2_d(const unsigned short* __restrict__ y2,
                                            const unsigned short* __restrict__ tbl,
                                            float* __restrict__ out) {
    const int tid = threadIdx.x;
    const int blk = blockIdx.x;            // bc*12 + quad
    const int bc = blk / 12;
    const int quad = blk % 12;
    const int g = __builtin_amdgcn_readfirstlane(tid >> 6);
    const int l = tid & 63;
    const int r = l & 15;
    const int kq = l >> 4;
    const int a1 = quad * 4 + g;

    const unsigned short* yb = y2 + ((size_t)bc * 64 * 48 + a1) * 48;

    f32x4 z = {0.f, 0.f, 0.f, 0.f};
    f32x4 acc[3][3];
    #pragma unroll
    for (int m = 0; m < 3; ++m)
        #pragma unroll
        for (int n = 0; n < 3; ++n) acc[m][n] = z;

    #pragma unroll
    for (int n = 0; n < 3; ++n) {
        #pragma unroll
        for (int ks = 0; ks < 2; ++ks) {
            short8 bf;
            #pragma unroll
            for (int j = 0; j < 8; ++j) {
                int d = 8 * kq + j + 32 * ks;
                bf[j] = (short)yb[(size_t)d * 2304 + 16 * n + r];   // gather (L1/L2/L3-hot)
            }
            #pragma unroll
            for (int m = 0; m < 3; ++m) {
                short8 ah = ldtbl(tbl, 0, ks, m, l);
                short8 al = ldtbl(tbl, 1, ks, m, l);
                acc[m][n] = __builtin_amdgcn_mfma_f32_16x16x32_bf16(ah, bf, acc[m][n], 0, 0, 0);
                acc[m][n] = __builtin_amdgcn_mfma_f32_16x16x32_bf16(al, bf, acc[m][n], 0, 0, 0);
            }
        }
    }
    #pragma unroll
    for (int m = 0; m < 3; ++m)
        #pragma unroll
        for (int n = 0; n < 3; ++n)
            #pragma unroll
            for (int rr = 0; rr < 4; ++rr) {
                int a0 = 16 * m + 4 * kq + rr;
                out[((size_t)(bc * 48 + a0) * 48 + a1) * 48 + 16 * n + r] = acc[m][n][rr];
            }
}

extern "C" void kernel_launch(void* const* d_in, const int* in_sizes, int n_in,
                              void* d_out, int out_size, void* d_ws, size_t ws_size,
                              hipStream_t stream) {
    const float* x = (const float*)d_in[0];
    float* out = (float*)d_out;

    unsigned short* tbl = (unsigned short*)d_ws;                     // 12 KiB
    unsigned short* y2 = (unsigned short*)((char*)d_ws + 65536);     // 36.75 MiB bf16

    gen_tbl<<<12, 256, 0, stream>>>(tbl);
    k1_wh<<<128 * 64, 256, 0, stream>>>(x, tbl, y2);
    k2_d<<<128 * 12, 256, 0, stream>>>(y2, tbl, out);
}